// Round 8
// baseline (205.997 us; speedup 1.0000x reference)
//
#include <hip/hip_runtime.h>
#include <math.h>

// ---------------------------------------------------------------------------
// GMM log-likelihood, N=2M x D=16, K=32, out = mean_n logsumexp_k loglik[n,k]
//
// loglik[n,k] = -0.5 (x)^T P_k x ... expanded LINEAR in features of x, fed to
// chained mfma_f32_32x32x16_f16 (M=32 = all comps at once).
//
// R8: P is SYMMETRIC -> ordered-pair features were 2x redundant. New packing,
// K = 160 (10 chunks) instead of 288 (18):
//   chunk d in [0,8): slot k16=8h+v -> feature x_i * x_{(i+d) mod 16}, i=k16
//       coeff: d==0: -0.5 P[i][i]/ln2 ; d>=1: -P[i][j]/ln2 (unordered pair
//       appears exactly once for gaps 1..7)
//   chunk 8: h=0 slots: pairs (v, v+8) gap-8, coeff -P[v][v+8]/ln2
//            h=1 slots: linear x_v, coeff (P mu)_v/ln2
//   chunk 9: h=0 slots: linear x_{8+v}; h=1: v==0 -> const c2[m], else 0
// Rotated operand built from own/other half-pairs with STATIC indices
// (u[] = [own0..3, other0..3]; even d: reindex, odd d: 1 v_perm align).
// MFMA/pair-iter: 36 -> 20 (pipe floor 14.8 -> 8.2 us/SIMD).
// W regs 72 -> 40 -> fits __launch_bounds__(256,3): 12 waves/CU (~170 reg
// budget, ~135 live) for 1.5x latency hiding. GRID 768 = 3 blocks/CU.
//
// C layout (HW-verified): col=lane&31 (point), row=(reg&3)+8*(reg>>2)+4*(lane>>5).
// Lane pair (l, l^32) holds all 32 comps of a point; combined via
// v_permlane32_swap (VALU-only; ds shuffles cost ~62 conflict-cyc each, R2).
// Half-split point loads (R7): lo lane owns x0..7, hi lane x8..15.
// ---------------------------------------------------------------------------

#define LOG_2PI 1.8378770664093453f
#define INV_LN2 1.4426950408889634f
#define LN2_D   0.6931471805599453

typedef float    float4v __attribute__((ext_vector_type(4)));
typedef float    f32x16  __attribute__((ext_vector_type(16)));
typedef _Float16 f16x8   __attribute__((ext_vector_type(8)));
typedef _Float16 f16x2   __attribute__((ext_vector_type(2)));

union H8 { f16x8 h8; f16x2 h2[4]; };

#if __has_builtin(__builtin_amdgcn_exp2f)
#define EXP2F(x) __builtin_amdgcn_exp2f(x)
#else
#define EXP2F(x) exp2f(x)
#endif
#if __has_builtin(__builtin_amdgcn_logf)
#define LOG2F(x) __builtin_amdgcn_logf(x)
#else
#define LOG2F(x) log2f(x)
#endif

static __device__ __forceinline__ f16x2 pk2(float a, float b) {
#if __has_builtin(__builtin_amdgcn_cvt_pkrtz)
  return __builtin_bit_cast(f16x2, __builtin_amdgcn_cvt_pkrtz(a, b));
#else
  f16x2 r; r[0] = (_Float16)a; r[1] = (_Float16)b; return r;
#endif
}

// partner-lane (lane^32) value of a 32-bit payload, VALU-only on gfx950
static __device__ __forceinline__ unsigned swapd(unsigned u, bool lo) {
#if __has_builtin(__builtin_amdgcn_permlane32_swap)
  typedef unsigned u32x2 __attribute__((ext_vector_type(2)));
  u32x2 r = __builtin_amdgcn_permlane32_swap(u, u, false, false);
  return lo ? r[1] : r[0];
#else
  return (unsigned)__shfl_xor((int)u, 32, 64);
#endif
}
static __device__ __forceinline__ float partner32(float x, bool lo) {
  return __builtin_bit_cast(float, swapd(__builtin_bit_cast(unsigned, x), lo));
}
static __device__ __forceinline__ f16x2 swap2(f16x2 v, bool lo) {
  return __builtin_bit_cast(f16x2, swapd(__builtin_bit_cast(unsigned, v), lo));
}
static __device__ __forceinline__ f16x2 sel2(bool c, f16x2 a, f16x2 b) {
  unsigned ua = __builtin_bit_cast(unsigned, a);
  unsigned ub = __builtin_bit_cast(unsigned, b);
  return __builtin_bit_cast(f16x2, c ? ua : ub);
}

// ---------------------------------------------------------------------------
// Setup: per component m (block): cov = A A^T, Cholesky L, Linv, P.
// W in 32x32x16 A-frag order: lane l holds A[comp = l&31][k16 = 8*(l>>5)+v].
// Chunk/feature mapping per header comment. Buffer: W[(c*64 + l)*8 + v].
// ---------------------------------------------------------------------------
__global__ void setup_kernel(const float* __restrict__ means,
                             const float* __restrict__ cov_parts,
                             const float* __restrict__ log_weights,
                             _Float16* __restrict__ W)
{
  const int m = blockIdx.x;
  const int i = threadIdx.x;

  __shared__ float sA[16][17];
  __shared__ float sC[16][17];
  __shared__ float sMu[16];
  __shared__ float sR[16];

  if (i < 16) {
    #pragma unroll
    for (int j = 0; j < 16; ++j) sA[i][j] = cov_parts[(m*16 + i)*16 + j];
    sMu[i] = means[m*16 + i];
  }
  __syncthreads();

  if (i < 16) {
    #pragma unroll
    for (int j = 0; j < 16; ++j) {
      float acc = 0.f;
      #pragma unroll
      for (int l = 0; l < 16; ++l) acc += sA[i][l] * sA[j][l];
      sC[i][j] = acc;
    }
  }
  __syncthreads();

  for (int j = 0; j < 16; ++j) {         // in-place Cholesky (lower)
    if (i == j) {
      float d = sC[j][j];
      for (int l = 0; l < j; ++l) d -= sC[j][l]*sC[j][l];
      sC[j][j] = sqrtf(d);
    }
    __syncthreads();
    if (i < 16 && i > j) {
      float a = sC[i][j];
      for (int l = 0; l < j; ++l) a -= sC[i][l]*sC[j][l];
      sC[i][j] = a / sC[j][j];
    }
    __syncthreads();
  }

  if (i < 16) {                          // Linv column i -> sA[:, i]
    float y[16];
    #pragma unroll
    for (int r = 0; r < 16; ++r) {
      float a = (r == i) ? 1.f : 0.f;
      #pragma unroll
      for (int l = 0; l < r; ++l) a -= sC[r][l] * y[l];
      y[r] = a / sC[r][r];
    }
    #pragma unroll
    for (int r = 0; r < 16; ++r) sA[r][i] = y[r];
  }
  __syncthreads();

  if (i < 16) {
    float p[16];                         // P row i
    #pragma unroll
    for (int j = 0; j < 16; ++j) {
      float acc = 0.f;
      #pragma unroll
      for (int l = 0; l < 16; ++l) acc += sA[l][i] * sA[l][j];
      p[j] = acc;
    }
    float ri = 0.f;
    #pragma unroll
    for (int j = 0; j < 16; ++j) ri += p[j] * sMu[j];
    sR[i] = ri;
    __syncthreads();                     // sR complete for all

    const int h = i >> 3, v = i & 7;
    const int lw_ = m + 32*h;
    // chunks 0..7: this thread writes coeff for feature (i, (i+d)&15)
    #pragma unroll
    for (int d = 0; d < 8; ++d) {
      float sc = (d == 0) ? -0.5f*INV_LN2 : -INV_LN2;
      W[(size_t)(d*64 + lw_)*8 + v] = (_Float16)(sc * p[(i + d) & 15]);
    }
    // chunk 8
    if (h == 0) W[(size_t)(8*64 + m)*8      + v] = (_Float16)(-INV_LN2 * p[i + 8]);
    else        W[(size_t)(8*64 + m + 32)*8 + v] = (_Float16)( INV_LN2 * sR[v]);
    // chunk 9
    float logdet = 0.f, mupmu = 0.f;
    #pragma unroll
    for (int j = 0; j < 16; ++j) { logdet += __logf(sC[j][j]); mupmu += sMu[j]*sR[j]; }
    float lwv = log_weights[m];
    float c2v = INV_LN2 * (-0.5f*(mupmu + 16.f*LOG_2PI) - logdet + lwv*lwv);
    if (h == 0) W[(size_t)(9*64 + m)*8      + v] = (_Float16)(INV_LN2 * sR[8 + v]);
    else        W[(size_t)(9*64 + m + 32)*8 + v] = (v == 0) ? (_Float16)c2v : (_Float16)0.f;
  }
}

// ---------------------------------------------------------------------------
__global__ __launch_bounds__(256, 3) void main_kernel(
    const float* __restrict__ data,
    const _Float16* __restrict__ W,
    float* __restrict__ partials,
    int npairs)
{
  const int lane = threadIdx.x & 63;
  const int n32  = lane & 31;
  const bool lo  = lane < 32;
  const int gwave  = (int)((blockIdx.x * blockDim.x + threadIdx.x) >> 6);
  const int nwaves = (int)((gridDim.x * blockDim.x) >> 6);

  // W fragments resident in registers (10 x 4 = 40 regs)
  f16x8 Wf[10];
  #pragma unroll
  for (int c = 0; c < 10; ++c)
    Wf[c] = *(const f16x8*)(W + (size_t)(c*64 + lane)*8);

  const f16x2 kOne  = pk2(1.f, 0.f);
  const f16x2 kZero = pk2(0.f, 0.f);

  float accsum = 0.f;

  // pair p covers points [p*64, p*64+64): tile A point = p*64+n32 (own half
  // at +h*32), tile B point = p*64+32+n32 (+2048). Half-split loads (R7).
  const char* base = (const char*)data + ((size_t)n32*64 + (lo ? 0 : 32));
  auto paddr = [&](int p) { return base + (size_t)p*4096; };

  float4v sa0[2], sa1[2], sb0[2], sb1[2];   // 2 staging slots, 32 B/lane each
  {
    const char* q0 = (gwave          < npairs) ? paddr(gwave)          : base;
    const char* q1 = (gwave + nwaves < npairs) ? paddr(gwave + nwaves) : base;
    sa0[0] = *(const float4v*)(q0);        sa1[0] = *(const float4v*)(q0 + 16);
    sb0[0] = *(const float4v*)(q0 + 2048); sb1[0] = *(const float4v*)(q0 + 2064);
    sa0[1] = *(const float4v*)(q1);        sa1[1] = *(const float4v*)(q1 + 16);
    sb0[1] = *(const float4v*)(q1 + 2048); sb1[1] = *(const float4v*)(q1 + 2064);
  }

  int p = gwave;
  while (p < npairs) {
    #pragma unroll
    for (int slot = 0; slot < 2; ++slot) {
      if (p >= npairs) break;

      // u[] = [own pairs 0..3, other pairs 4..7] (cyclic from this lane's view)
      f16x2 uA[8], uB[8];
      uA[0] = pk2(sa0[slot][0], sa0[slot][1]);
      uA[1] = pk2(sa0[slot][2], sa0[slot][3]);
      uA[2] = pk2(sa1[slot][0], sa1[slot][1]);
      uA[3] = pk2(sa1[slot][2], sa1[slot][3]);
      uB[0] = pk2(sb0[slot][0], sb0[slot][1]);
      uB[1] = pk2(sb0[slot][2], sb0[slot][3]);
      uB[2] = pk2(sb1[slot][0], sb1[slot][1]);
      uB[3] = pk2(sb1[slot][2], sb1[slot][3]);
      #pragma unroll
      for (int j = 0; j < 4; ++j) {
        uA[4+j] = swap2(uA[j], lo);
        uB[4+j] = swap2(uB[j], lo);
      }

      { // reload this slot for pair p + 2*nwaves (wave-uniform guard)
        int np_ = p + 2*nwaves;
        const char* q = (np_ < npairs) ? paddr(np_) : base;
        sa0[slot] = *(const float4v*)(q);        sa1[slot] = *(const float4v*)(q + 16);
        sb0[slot] = *(const float4v*)(q + 2048); sb1[slot] = *(const float4v*)(q + 2064);
      }

      f32x16 accA, accB;
      #pragma unroll
      for (int r = 0; r < 16; ++r) { accA[r] = 0.f; accB[r] = 0.f; }

      #pragma unroll
      for (int d = 0; d < 9; ++d) {      // rotation chunks (incl. gap-8)
        H8 bA, bB;
        #pragma unroll
        for (int j = 0; j < 4; ++j) {
          const int o = 2*j + d;         // compile-time after unroll
          f16x2 rA, rB;
          if ((d & 1) == 0) { rA = uA[o >> 1]; rB = uB[o >> 1]; }
          else {
            rA = __builtin_shufflevector(uA[(o-1) >> 1], uA[(o+1) >> 1], 1, 2);
            rB = __builtin_shufflevector(uB[(o-1) >> 1], uB[(o+1) >> 1], 1, 2);
          }
          f16x2 pA = uA[j] * rA;         // v_pk_mul_f16
          f16x2 pB = uB[j] * rB;
          if (d == 8) {                  // hi half supplies linear x_0..7
            pA = sel2(lo, pA, uA[4+j]);
            pB = sel2(lo, pB, uB[4+j]);
          }
          bA.h2[j] = pA; bB.h2[j] = pB;
        }
        accA = __builtin_amdgcn_mfma_f32_32x32x16_f16(Wf[d], bA.h8, accA, 0, 0, 0);
        accB = __builtin_amdgcn_mfma_f32_32x32x16_f16(Wf[d], bB.h8, accB, 0, 0, 0);
      }
      { // chunk 9: lo: linear x_8..15 ; hi: [1 (c2), 0, 0, 0]
        H8 bA, bB;
        bA.h2[0] = sel2(lo, uA[4], kOne);
        bB.h2[0] = sel2(lo, uB[4], kOne);
        #pragma unroll
        for (int j = 1; j < 4; ++j) {
          bA.h2[j] = sel2(lo, uA[4+j], kZero);
          bB.h2[j] = sel2(lo, uB[4+j], kZero);
        }
        accA = __builtin_amdgcn_mfma_f32_32x32x16_f16(Wf[9], bA.h8, accA, 0, 0, 0);
        accB = __builtin_amdgcn_mfma_f32_32x32x16_f16(Wf[9], bB.h8, accB, 0, 0, 0);
      }

      // epilogue: logsumexp (log2 domain), acc already includes c2
      {
        float mx = accA[0];
        #pragma unroll
        for (int r = 1; r < 16; ++r) mx = fmaxf(mx, accA[r]);
        mx = fmaxf(mx, partner32(mx, lo));
        float s = 0.f;
        #pragma unroll
        for (int r = 0; r < 16; ++r) s += EXP2F(accA[r] - mx);
        s += partner32(s, lo);
        accsum += mx + LOG2F(s);
      }
      {
        float mx = accB[0];
        #pragma unroll
        for (int r = 1; r < 16; ++r) mx = fmaxf(mx, accB[r]);
        mx = fmaxf(mx, partner32(mx, lo));
        float s = 0.f;
        #pragma unroll
        for (int r = 0; r < 16; ++r) s += EXP2F(accB[r] - mx);
        s += partner32(s, lo);
        accsum += mx + LOG2F(s);
      }

      p += nwaves;
    }
  }

  #pragma unroll
  for (int off = 1; off <= 32; off <<= 1)
    accsum += __shfl_xor(accsum, off, 64);

  __shared__ float wsum[4];
  const int wid = (int)(threadIdx.x >> 6);
  if ((threadIdx.x & 63) == 0) wsum[wid] = accsum;
  __syncthreads();
  if (threadIdx.x == 0)
    partials[blockIdx.x] = wsum[0] + wsum[1] + wsum[2] + wsum[3];
}

// ---------------------------------------------------------------------------
__global__ void reduce_kernel(const float* __restrict__ partials, int n,
                              float* __restrict__ out, double scale)
{
  __shared__ double sd[256];
  double a = 0.0;
  for (int idx = threadIdx.x; idx < n; idx += 256) a += (double)partials[idx];
  sd[threadIdx.x] = a;
  __syncthreads();
  for (int s = 128; s > 0; s >>= 1) {
    if ((int)threadIdx.x < s) sd[threadIdx.x] += sd[threadIdx.x + s];
    __syncthreads();
  }
  if (threadIdx.x == 0) out[0] = (float)(sd[0] * scale);
}

extern "C" void kernel_launch(void* const* d_in, const int* in_sizes, int n_in,
                              void* d_out, int out_size, void* d_ws, size_t ws_size,
                              hipStream_t stream)
{
  const float* data        = (const float*)d_in[0];
  const float* means       = (const float*)d_in[1];
  const float* cov_parts   = (const float*)d_in[2];
  const float* log_weights = (const float*)d_in[3];

  const int npts   = in_sizes[0] / 16;
  const int npairs = npts / 64;        // N = 2,000,000 divisible by 64

  _Float16* W      = (_Float16*)d_ws;                          // 10*64*8 halfs
  float*    partials = (float*)((char*)d_ws + (size_t)10*64*8*sizeof(_Float16));

  const int GRID = 768, BLOCK = 256;   // 3 blocks/CU, 12 waves/CU
  setup_kernel<<<32, 64, 0, stream>>>(means, cov_parts, log_weights, W);
  main_kernel<<<GRID, BLOCK, 0, stream>>>(data, W, partials, npairs);
  reduce_kernel<<<1, 256, 0, stream>>>(partials, GRID, (float*)d_out,
                                       LN2_D / (2.0 * (double)npts));
}